// Round 2
// baseline (695.242 us; speedup 1.0000x reference)
//
#include <hip/hip_runtime.h>
#include <stdint.h>

#define SIZE 65535

typedef __bf16 bf16x8 __attribute__((ext_vector_type(8)));
typedef float floatx4 __attribute__((ext_vector_type(4)));

// ws layout (bf16 elements):
#define WS_ENCW 0        // [128][256] -> 32768
#define WS_WIH  32768    // [384][128] -> 49152
#define WS_WHH  81920    // [384][128] -> 49152
#define WS_VW   131072   // [64][128]  -> 8192
#define WS_DECW 139264   // [10][192]  -> 1920
#define WS_TOT  141184

__device__ __forceinline__ unsigned short f2bf(float f) {
    union { float f; unsigned int u; } v; v.f = f;
    unsigned int u = v.u;
    return (unsigned short)((u + 0x7fffu + ((u >> 16) & 1u)) >> 16);
}
__device__ __forceinline__ float bf2f(unsigned short b) {
    union { unsigned int u; float f; } v; v.u = ((unsigned int)b) << 16;
    return v.f;
}
__device__ __forceinline__ float sigmf(float x) {
    x = fminf(fmaxf(x, -30.f), 30.f);
    return 1.f / (1.f + __expf(-x));
}
__device__ __forceinline__ float tanhfast(float x) {
    x = fminf(fmaxf(x, -15.f), 15.f);
    float e = __expf(2.f * x);
    return (e - 1.f) / (e + 1.f);
}

union BF8 { bf16x8 v; unsigned short s[8]; };

// load 8 f32 from global, round-to-nearest-even to bf16x8
__device__ __forceinline__ bf16x8 cvt8g(const float* p) {
    float4 a = *reinterpret_cast<const float4*>(p);
    float4 b = *reinterpret_cast<const float4*>(p + 4);
    BF8 r;
    r.s[0] = f2bf(a.x); r.s[1] = f2bf(a.y); r.s[2] = f2bf(a.z); r.s[3] = f2bf(a.w);
    r.s[4] = f2bf(b.x); r.s[5] = f2bf(b.y); r.s[6] = f2bf(b.z); r.s[7] = f2bf(b.w);
    return r.v;
}
__device__ __forceinline__ bf16x8 ld8(const unsigned short* p) {
    return *reinterpret_cast<const bf16x8*>(p);
}

// ---------- pre-kernel: convert live f32 weights to bf16 in d_ws ----------
__global__ __launch_bounds__(256) void cvt_weights(
    const float* __restrict__ enc_w, const float* __restrict__ w_ih,
    const float* __restrict__ w_hh, const float* __restrict__ v_w,
    const float* __restrict__ dec_w, unsigned short* __restrict__ ws) {
    int i = blockIdx.x * 256 + threadIdx.x;
    if (i >= WS_TOT) return;
    const float* src; int off;
    if (i < WS_WIH)       { src = enc_w; off = WS_ENCW; }
    else if (i < WS_WHH)  { src = w_ih;  off = WS_WIH; }
    else if (i < WS_VW)   { src = w_hh;  off = WS_WHH; }
    else if (i < WS_DECW) { src = v_w;   off = WS_VW; }
    else                  { src = dec_w; off = WS_DECW; }
    ws[i] = f2bf(src[i - off]);
}

// ---------- main fused kernel ----------
// Dead code eliminated: bi-GRU / gumbel hard attention / q,k (softmax over a
// singleton axis == 1, so x_att == v). Live: enc -> GRU cell -> v -> dec.
// 256 blocks x 4 waves x 64 rows (4 m-tiles of 16). Weights bf16 from d_ws,
// read once per wave; activations f32 in / f32 out, bf16 MFMA operands.
__global__ __launch_bounds__(256) void attn_critic_kernel(
    const float* __restrict__ obs,    // [SIZE,256] f32
    const float* __restrict__ hid,    // [SIZE,128] f32
    const float* __restrict__ enc_b,  // [128] f32
    const float* __restrict__ b_ih,   // [384] f32
    const float* __restrict__ b_hh,   // [384] f32
    const float* __restrict__ v_b,    // [64] f32
    const float* __restrict__ dec_b,  // [10] f32
    const unsigned short* __restrict__ wsw,  // bf16 weights (ws layout)
    float* __restrict__ out)          // [SIZE*10] ++ [SIZE*128] f32
{
    __shared__ __align__(16) unsigned short sX[4][16][128];   // x   (C->A xform)
    __shared__ __align__(16) unsigned short sH[4][16][128];   // h_prev (for pointwise)
    __shared__ __align__(16) unsigned short sHV[4][16][192];  // [h_out | v]

    const unsigned short* encw = wsw + WS_ENCW;
    const unsigned short* wih  = wsw + WS_WIH;
    const unsigned short* whh  = wsw + WS_WHH;
    const unsigned short* vw   = wsw + WS_VW;
    const unsigned short* decw = wsw + WS_DECW;

    const int tid  = threadIdx.x;
    const int wave = tid >> 6;
    const int lane = tid & 63;
    const int l15  = lane & 15;
    const int quad = lane >> 4;
    const int wrow0 = (blockIdx.x * 4 + wave) * 64;
    float* out_h = out + (size_t)SIZE * 10;

    for (int m = 0; m < 4; ++m) {
        const int mrow0 = wrow0 + m * 16;
        int rA = mrow0 + l15;
        const int rowA = (rA < SIZE) ? rA : (SIZE - 1);

        // ---- Phase 1: X = relu(OBS @ enc_w^T + enc_b) ----
        floatx4 accx[8];
#pragma unroll
        for (int nt = 0; nt < 8; ++nt) accx[nt] = floatx4{0.f, 0.f, 0.f, 0.f};
        const float* obsrow = obs + (size_t)rowA * 256;
#pragma unroll
        for (int kt = 0; kt < 8; ++kt) {
            bf16x8 a = cvt8g(obsrow + kt * 32 + quad * 8);
#pragma unroll
            for (int nt = 0; nt < 8; ++nt) {
                bf16x8 b = ld8(encw + (nt * 16 + l15) * 256 + kt * 32 + quad * 8);
                accx[nt] = __builtin_amdgcn_mfma_f32_16x16x32_bf16(a, b, accx[nt], 0, 0, 0);
            }
        }
#pragma unroll
        for (int nt = 0; nt < 8; ++nt) {
            float bias = enc_b[nt * 16 + l15];
#pragma unroll
            for (int r = 0; r < 4; ++r)
                sX[wave][quad * 4 + r][nt * 16 + l15] =
                    f2bf(fmaxf(accx[nt][r] + bias, 0.f));
        }
        // stage h_prev (bf16) while phase-1 results settle
        bf16x8 hf[4], xf[4];
        const float* hidrow = hid + (size_t)rowA * 128;
#pragma unroll
        for (int kt = 0; kt < 4; ++kt) {
            hf[kt] = cvt8g(hidrow + kt * 32 + quad * 8);
            *reinterpret_cast<bf16x8*>(&sH[wave][l15][kt * 32 + quad * 8]) = hf[kt];
        }
        __syncthreads();
#pragma unroll
        for (int kt = 0; kt < 4; ++kt)
            xf[kt] = ld8(&sX[wave][l15][kt * 32 + quad * 8]);

        // ---- Phase 2: GRU cell ----
#pragma unroll
        for (int nt = 0; nt < 8; ++nt) {
            const int nr = nt * 16 + l15;
            floatx4 gir = floatx4{0.f,0.f,0.f,0.f}, giz = gir, gin = gir;
            floatx4 ghr = gir, ghz = gir, ghn = gir;
#pragma unroll
            for (int kt = 0; kt < 4; ++kt) {
                const int ko = kt * 32 + quad * 8;
                bf16x8 bir = ld8(wih + (size_t)(nr)       * 128 + ko);
                bf16x8 biz = ld8(wih + (size_t)(nr + 128) * 128 + ko);
                bf16x8 bin = ld8(wih + (size_t)(nr + 256) * 128 + ko);
                gir = __builtin_amdgcn_mfma_f32_16x16x32_bf16(xf[kt], bir, gir, 0, 0, 0);
                giz = __builtin_amdgcn_mfma_f32_16x16x32_bf16(xf[kt], biz, giz, 0, 0, 0);
                gin = __builtin_amdgcn_mfma_f32_16x16x32_bf16(xf[kt], bin, gin, 0, 0, 0);
                bf16x8 bhr = ld8(whh + (size_t)(nr)       * 128 + ko);
                bf16x8 bhz = ld8(whh + (size_t)(nr + 128) * 128 + ko);
                bf16x8 bhn = ld8(whh + (size_t)(nr + 256) * 128 + ko);
                ghr = __builtin_amdgcn_mfma_f32_16x16x32_bf16(hf[kt], bhr, ghr, 0, 0, 0);
                ghz = __builtin_amdgcn_mfma_f32_16x16x32_bf16(hf[kt], bhz, ghz, 0, 0, 0);
                ghn = __builtin_amdgcn_mfma_f32_16x16x32_bf16(hf[kt], bhn, ghn, 0, 0, 0);
            }
            const float bir_ = b_ih[nr], biz_ = b_ih[nr + 128], bin_ = b_ih[nr + 256];
            const float bhr_ = b_hh[nr], bhz_ = b_hh[nr + 128], bhn_ = b_hh[nr + 256];
#pragma unroll
            for (int r = 0; r < 4; ++r) {
                const int grow = mrow0 + quad * 4 + r;
                float hprev = bf2f(sH[wave][quad * 4 + r][nr]);
                float rg = sigmf(gir[r] + bir_ + ghr[r] + bhr_);
                float zg = sigmf(giz[r] + biz_ + ghz[r] + bhz_);
                float ng = tanhfast(gin[r] + bin_ + rg * (ghn[r] + bhn_));
                float ho = (1.f - zg) * ng + zg * hprev;
                if (grow < SIZE) out_h[(size_t)grow * 128 + nr] = ho;
                sHV[wave][quad * 4 + r][nr] = f2bf(ho);
            }
        }
        __syncthreads();

        // ---- Phase 3: V = relu(H_OUT @ v_w^T + v_b) ----
        bf16x8 af[4];
#pragma unroll
        for (int kt = 0; kt < 4; ++kt)
            af[kt] = ld8(&sHV[wave][l15][kt * 32 + quad * 8]);
#pragma unroll
        for (int nt = 0; nt < 4; ++nt) {
            floatx4 acc = floatx4{0.f, 0.f, 0.f, 0.f};
#pragma unroll
            for (int kt = 0; kt < 4; ++kt) {
                bf16x8 b = ld8(vw + (nt * 16 + l15) * 128 + kt * 32 + quad * 8);
                acc = __builtin_amdgcn_mfma_f32_16x16x32_bf16(af[kt], b, acc, 0, 0, 0);
            }
            float bias = v_b[nt * 16 + l15];
#pragma unroll
            for (int r = 0; r < 4; ++r)
                sHV[wave][quad * 4 + r][128 + nt * 16 + l15] =
                    f2bf(fmaxf(acc[r] + bias, 0.f));
        }
        __syncthreads();

        // ---- Phase 4: OUT = [H_OUT|V] @ dec_w^T + dec_b ----
        {
            floatx4 accd = floatx4{0.f, 0.f, 0.f, 0.f};
            const int wr = (l15 < 10) ? l15 : 9;
#pragma unroll
            for (int kt = 0; kt < 6; ++kt) {
                bf16x8 a = ld8(&sHV[wave][l15][kt * 32 + quad * 8]);
                bf16x8 b = ld8(decw + wr * 192 + kt * 32 + quad * 8);
                accd = __builtin_amdgcn_mfma_f32_16x16x32_bf16(a, b, accd, 0, 0, 0);
            }
            if (l15 < 10) {
                float bias = dec_b[l15];
#pragma unroll
                for (int r = 0; r < 4; ++r) {
                    int grow = mrow0 + quad * 4 + r;
                    if (grow < SIZE) out[(size_t)grow * 10 + l15] = accd[r] + bias;
                }
            }
        }
        __syncthreads();
    }
}

extern "C" void kernel_launch(void* const* d_in, const int* in_sizes, int n_in,
                              void* d_out, int out_size, void* d_ws, size_t ws_size,
                              hipStream_t stream) {
    const float* obs   = (const float*)d_in[0];
    const float* hid   = (const float*)d_in[1];
    const float* enc_w = (const float*)d_in[2];
    const float* enc_b = (const float*)d_in[3];
    const float* w_ih  = (const float*)d_in[4];
    const float* w_hh  = (const float*)d_in[5];
    const float* b_ih  = (const float*)d_in[6];
    const float* b_hh  = (const float*)d_in[7];
    // d_in[8..19]: bi-GRU / hard-attention / q,k weights — dead code, unused.
    const float* v_w   = (const float*)d_in[20];
    const float* v_b   = (const float*)d_in[21];
    const float* dec_w = (const float*)d_in[22];
    const float* dec_b = (const float*)d_in[23];
    unsigned short* wsw = (unsigned short*)d_ws;
    float* out = (float*)d_out;

    hipLaunchKernelGGL(cvt_weights, dim3((WS_TOT + 255) / 256), dim3(256), 0, stream,
                       enc_w, w_ih, w_hh, v_w, dec_w, wsw);
    // 256 blocks x 4 waves x 64 rows = 65536 >= 65535
    hipLaunchKernelGGL(attn_critic_kernel, dim3(256), dim3(256), 0, stream,
                       obs, hid, enc_b, b_ih, b_hh, v_b, dec_b, wsw, out);
}

// Round 3
// 292.363 us; speedup vs baseline: 2.3780x; 2.3780x over previous
//
#include <hip/hip_runtime.h>
#include <stdint.h>

#define SIZE 65535

typedef __bf16 bf16x8 __attribute__((ext_vector_type(8)));
typedef float floatx4 __attribute__((ext_vector_type(4)));

// ws layout (bf16 elements):
#define WS_ENCW 0        // [128][256] -> 32768
#define WS_WIH  32768    // [384][128] -> 49152
#define WS_WHH  81920    // [384][128] -> 49152
#define WS_VW   131072   // [64][128]  -> 8192
#define WS_DECW 139264   // [10][192]  -> 1920
#define WS_TOT  141184

__device__ __forceinline__ unsigned short f2bf(float f) {
    union { float f; unsigned int u; } v; v.f = f;
    unsigned int u = v.u;
    return (unsigned short)((u + 0x7fffu + ((u >> 16) & 1u)) >> 16);
}
__device__ __forceinline__ float bf2f(unsigned short b) {
    union { unsigned int u; float f; } v; v.u = ((unsigned int)b) << 16;
    return v.f;
}
__device__ __forceinline__ float sigmf(float x) {
    x = fminf(fmaxf(x, -30.f), 30.f);
    return 1.f / (1.f + __expf(-x));
}
__device__ __forceinline__ float tanhfast(float x) {
    x = fminf(fmaxf(x, -15.f), 15.f);
    float e = __expf(2.f * x);
    return (e - 1.f) / (e + 1.f);
}

union BF8 { bf16x8 v; unsigned short s[8]; };

__device__ __forceinline__ bf16x8 cvt8g(const float* p) {
    float4 a = *reinterpret_cast<const float4*>(p);
    float4 b = *reinterpret_cast<const float4*>(p + 4);
    BF8 r;
    r.s[0] = f2bf(a.x); r.s[1] = f2bf(a.y); r.s[2] = f2bf(a.z); r.s[3] = f2bf(a.w);
    r.s[4] = f2bf(b.x); r.s[5] = f2bf(b.y); r.s[6] = f2bf(b.z); r.s[7] = f2bf(b.w);
    return r.v;
}
__device__ __forceinline__ bf16x8 ld8(const unsigned short* p) {
    return *reinterpret_cast<const bf16x8*>(p);
}

// ---------- pre-kernel: convert live f32 weights to bf16 in d_ws ----------
__global__ __launch_bounds__(256) void cvt_weights(
    const float* __restrict__ enc_w, const float* __restrict__ w_ih,
    const float* __restrict__ w_hh, const float* __restrict__ v_w,
    const float* __restrict__ dec_w, unsigned short* __restrict__ ws) {
    int i = blockIdx.x * 256 + threadIdx.x;
    if (i >= WS_TOT) return;
    const float* src; int off;
    if (i < WS_WIH)       { src = enc_w; off = WS_ENCW; }
    else if (i < WS_WHH)  { src = w_ih;  off = WS_WIH; }
    else if (i < WS_VW)   { src = w_hh;  off = WS_WHH; }
    else if (i < WS_DECW) { src = v_w;   off = WS_VW; }
    else                  { src = dec_w; off = WS_DECW; }
    ws[i] = f2bf(src[i - off]);
}

// ---------- main fused kernel ----------
// Live subgraph only: enc -> GRU cell -> v -> dec (bi-GRU / gumbel / q,k dead;
// softmax over singleton axis == 1 so x_att == v).
// 1024 blocks x 4 waves x 16 rows. Wave-private LDS slice, no __syncthreads.
// launch_bounds(256,4): cap 128 VGPR -> 16 waves/CU; outer loops unroll 1 to
// keep live B-fragment sets small (round-2 spilled at VGPR=256).
__global__ __launch_bounds__(256, 4) void attn_critic_kernel(
    const float* __restrict__ obs,    // [SIZE,256] f32
    const float* __restrict__ hid,    // [SIZE,128] f32
    const float* __restrict__ enc_b,  // [128] f32
    const float* __restrict__ b_ih,   // [384] f32
    const float* __restrict__ b_hh,   // [384] f32
    const float* __restrict__ v_b,    // [64] f32
    const float* __restrict__ dec_b,  // [10] f32
    const unsigned short* __restrict__ wsw,  // bf16 weights (ws layout)
    float* __restrict__ out)          // [SIZE*10] ++ [SIZE*128] f32
{
    // one aliased per-wave buffer: cols 0..127 hold x then h_out; 128..191 v
    __shared__ __align__(16) unsigned short sB[4][16][192];

    const unsigned short* encw = wsw + WS_ENCW;
    const unsigned short* wih  = wsw + WS_WIH;
    const unsigned short* whh  = wsw + WS_WHH;
    const unsigned short* vw   = wsw + WS_VW;
    const unsigned short* decw = wsw + WS_DECW;

    const int tid  = threadIdx.x;
    const int wave = tid >> 6;
    const int lane = tid & 63;
    const int l15  = lane & 15;
    const int quad = lane >> 4;
    const int row0 = (blockIdx.x * 4 + wave) * 16;
    const int rowA = (row0 + l15 < SIZE) ? (row0 + l15) : (SIZE - 1);
    unsigned short (*S)[192] = sB[wave];

    // ---- Phase 1: X = relu(OBS @ enc_w^T + enc_b) ----
    floatx4 accx[8];
#pragma unroll
    for (int nt = 0; nt < 8; ++nt) accx[nt] = floatx4{0.f, 0.f, 0.f, 0.f};
    const float* obsrow = obs + (size_t)rowA * 256;
#pragma unroll 1
    for (int kt = 0; kt < 8; ++kt) {
        bf16x8 a = cvt8g(obsrow + kt * 32 + quad * 8);
#pragma unroll
        for (int nt = 0; nt < 8; ++nt) {
            bf16x8 b = ld8(encw + (nt * 16 + l15) * 256 + kt * 32 + quad * 8);
            accx[nt] = __builtin_amdgcn_mfma_f32_16x16x32_bf16(a, b, accx[nt], 0, 0, 0);
        }
    }
#pragma unroll
    for (int nt = 0; nt < 8; ++nt) {
        float bias = enc_b[nt * 16 + l15];
#pragma unroll
        for (int r = 0; r < 4; ++r)
            S[quad * 4 + r][nt * 16 + l15] = f2bf(fmaxf(accx[nt][r] + bias, 0.f));
    }

    // A-fragments for phase 2
    bf16x8 hf[4], xf[4];
    const float* hidrow = hid + (size_t)rowA * 128;
#pragma unroll
    for (int kt = 0; kt < 4; ++kt) hf[kt] = cvt8g(hidrow + kt * 32 + quad * 8);
#pragma unroll
    for (int kt = 0; kt < 4; ++kt) xf[kt] = ld8(&S[l15][kt * 32 + quad * 8]);

    // ---- Phase 2: GRU cell (writes h_out back over x in S cols 0..127) ----
#pragma unroll 1
    for (int nt = 0; nt < 8; ++nt) {
        const int nr = nt * 16 + l15;
        floatx4 gir = floatx4{0.f,0.f,0.f,0.f}, giz = gir, gin = gir;
        floatx4 ghr = gir, ghz = gir, ghn = gir;
#pragma unroll
        for (int kt = 0; kt < 4; ++kt) {
            const int ko = kt * 32 + quad * 8;
            bf16x8 bir = ld8(wih + (size_t)(nr)       * 128 + ko);
            bf16x8 biz = ld8(wih + (size_t)(nr + 128) * 128 + ko);
            bf16x8 bin = ld8(wih + (size_t)(nr + 256) * 128 + ko);
            gir = __builtin_amdgcn_mfma_f32_16x16x32_bf16(xf[kt], bir, gir, 0, 0, 0);
            giz = __builtin_amdgcn_mfma_f32_16x16x32_bf16(xf[kt], biz, giz, 0, 0, 0);
            gin = __builtin_amdgcn_mfma_f32_16x16x32_bf16(xf[kt], bin, gin, 0, 0, 0);
            bf16x8 bhr = ld8(whh + (size_t)(nr)       * 128 + ko);
            bf16x8 bhz = ld8(whh + (size_t)(nr + 128) * 128 + ko);
            bf16x8 bhn = ld8(whh + (size_t)(nr + 256) * 128 + ko);
            ghr = __builtin_amdgcn_mfma_f32_16x16x32_bf16(hf[kt], bhr, ghr, 0, 0, 0);
            ghz = __builtin_amdgcn_mfma_f32_16x16x32_bf16(hf[kt], bhz, ghz, 0, 0, 0);
            ghn = __builtin_amdgcn_mfma_f32_16x16x32_bf16(hf[kt], bhn, ghn, 0, 0, 0);
        }
        const float bir_ = b_ih[nr], biz_ = b_ih[nr + 128], bin_ = b_ih[nr + 256];
        const float bhr_ = b_hh[nr], bhz_ = b_hh[nr + 128], bhn_ = b_hh[nr + 256];
#pragma unroll
        for (int r = 0; r < 4; ++r) {
            const int grow = row0 + quad * 4 + r;
            const int rowc = (grow < SIZE) ? grow : (SIZE - 1);
            float hprev = hid[(size_t)rowc * 128 + nr];  // f32, L1/L2-hot
            float rg = sigmf(gir[r] + bir_ + ghr[r] + bhr_);
            float zg = sigmf(giz[r] + biz_ + ghz[r] + bhz_);
            float ng = tanhfast(gin[r] + bin_ + rg * (ghn[r] + bhn_));
            float ho = (1.f - zg) * ng + zg * hprev;
            S[quad * 4 + r][nr] = f2bf(ho);
        }
    }

    // ---- h_out -> global, coalesced from LDS (f32 stores, 8B aligned) ----
    {
        float* hout_g = out + (size_t)SIZE * 10;
#pragma unroll 1
        for (int it = 0; it < 8; ++it) {
            int idx = it * 256 + lane * 4;  // of 16*128 elements
            int rr = idx >> 7, cc = idx & 127;
            int grow = row0 + rr;
            if (grow < SIZE) {
                float2 p0 = make_float2(bf2f(S[rr][cc]),     bf2f(S[rr][cc + 1]));
                float2 p1 = make_float2(bf2f(S[rr][cc + 2]), bf2f(S[rr][cc + 3]));
                float* dst = hout_g + (size_t)grow * 128 + cc;
                *reinterpret_cast<float2*>(dst)     = p0;
                *reinterpret_cast<float2*>(dst + 2) = p1;
            }
        }
    }

    // ---- Phase 3: V = relu(H_OUT @ v_w^T + v_b) -> S cols 128..191 ----
    bf16x8 af[4];
#pragma unroll
    for (int kt = 0; kt < 4; ++kt) af[kt] = ld8(&S[l15][kt * 32 + quad * 8]);
#pragma unroll 1
    for (int nt = 0; nt < 4; ++nt) {
        floatx4 acc = floatx4{0.f, 0.f, 0.f, 0.f};
#pragma unroll
        for (int kt = 0; kt < 4; ++kt) {
            bf16x8 b = ld8(vw + (nt * 16 + l15) * 128 + kt * 32 + quad * 8);
            acc = __builtin_amdgcn_mfma_f32_16x16x32_bf16(af[kt], b, acc, 0, 0, 0);
        }
        float bias = v_b[nt * 16 + l15];
#pragma unroll
        for (int r = 0; r < 4; ++r)
            S[quad * 4 + r][128 + nt * 16 + l15] = f2bf(fmaxf(acc[r] + bias, 0.f));
    }

    // ---- Phase 4: OUT = [H_OUT|V] @ dec_w^T + dec_b ----
    {
        floatx4 accd = floatx4{0.f, 0.f, 0.f, 0.f};
        const int wr = (l15 < 10) ? l15 : 9;
#pragma unroll
        for (int kt = 0; kt < 6; ++kt) {
            bf16x8 a = ld8(&S[l15][kt * 32 + quad * 8]);
            bf16x8 b = ld8(decw + wr * 192 + kt * 32 + quad * 8);
            accd = __builtin_amdgcn_mfma_f32_16x16x32_bf16(a, b, accd, 0, 0, 0);
        }
        if (l15 < 10) {
            float bias = dec_b[l15];
#pragma unroll
            for (int r = 0; r < 4; ++r) {
                int grow = row0 + quad * 4 + r;
                if (grow < SIZE) out[(size_t)grow * 10 + l15] = accd[r] + bias;
            }
        }
    }
}

extern "C" void kernel_launch(void* const* d_in, const int* in_sizes, int n_in,
                              void* d_out, int out_size, void* d_ws, size_t ws_size,
                              hipStream_t stream) {
    const float* obs   = (const float*)d_in[0];
    const float* hid   = (const float*)d_in[1];
    const float* enc_w = (const float*)d_in[2];
    const float* enc_b = (const float*)d_in[3];
    const float* w_ih  = (const float*)d_in[4];
    const float* w_hh  = (const float*)d_in[5];
    const float* b_ih  = (const float*)d_in[6];
    const float* b_hh  = (const float*)d_in[7];
    // d_in[8..19]: dead code (bi-GRU / hard attention / q,k) — unused.
    const float* v_w   = (const float*)d_in[20];
    const float* v_b   = (const float*)d_in[21];
    const float* dec_w = (const float*)d_in[22];
    const float* dec_b = (const float*)d_in[23];
    unsigned short* wsw = (unsigned short*)d_ws;
    float* out = (float*)d_out;

    hipLaunchKernelGGL(cvt_weights, dim3((WS_TOT + 255) / 256), dim3(256), 0, stream,
                       enc_w, w_ih, w_hh, v_w, dec_w, wsw);
    // 1024 blocks x 4 waves x 16 rows = 65536 >= 65535
    hipLaunchKernelGGL(attn_critic_kernel, dim3(1024), dim3(256), 0, stream,
                       obs, hid, enc_b, b_ih, b_hh, v_b, dec_b, wsw, out);
}

// Round 4
// 256.014 us; speedup vs baseline: 2.7156x; 1.1420x over previous
//
#include <hip/hip_runtime.h>
#include <stdint.h>

#define SIZE 65535

typedef __bf16 bf16x8 __attribute__((ext_vector_type(8)));
typedef float floatx4 __attribute__((ext_vector_type(4)));

// ws layout (bf16 elements):
#define WS_ENCW 0        // [128][256] -> 32768
#define WS_WIH  32768    // [384][128] -> 49152
#define WS_WHH  81920    // [384][128] -> 49152
#define WS_VW   131072   // [64][128]  -> 8192
#define WS_DECW 139264   // [10][192]  -> 1920
#define WS_TOT  141184

__device__ __forceinline__ unsigned short f2bf(float f) {
    union { float f; unsigned int u; } v; v.f = f;
    unsigned int u = v.u;
    return (unsigned short)((u + 0x7fffu + ((u >> 16) & 1u)) >> 16);
}
__device__ __forceinline__ float bf2f(unsigned short b) {
    union { unsigned int u; float f; } v; v.u = ((unsigned int)b) << 16;
    return v.f;
}
__device__ __forceinline__ float sigmf(float x) {
    x = fminf(fmaxf(x, -30.f), 30.f);
    return 1.f / (1.f + __expf(-x));
}
__device__ __forceinline__ float tanhfast(float x) {
    x = fminf(fmaxf(x, -15.f), 15.f);
    float e = __expf(2.f * x);
    return (e - 1.f) / (e + 1.f);
}

union BF8 { bf16x8 v; unsigned short s[8]; };

__device__ __forceinline__ bf16x8 cvt8g(const float* p) {
    float4 a = *reinterpret_cast<const float4*>(p);
    float4 b = *reinterpret_cast<const float4*>(p + 4);
    BF8 r;
    r.s[0] = f2bf(a.x); r.s[1] = f2bf(a.y); r.s[2] = f2bf(a.z); r.s[3] = f2bf(a.w);
    r.s[4] = f2bf(b.x); r.s[5] = f2bf(b.y); r.s[6] = f2bf(b.z); r.s[7] = f2bf(b.w);
    return r.v;
}
__device__ __forceinline__ bf16x8 ld8(const unsigned short* p) {
    return *reinterpret_cast<const bf16x8*>(p);
}

// ---------- pre-kernel: convert live f32 weights to bf16 in d_ws ----------
__global__ __launch_bounds__(256) void cvt_weights(
    const float* __restrict__ enc_w, const float* __restrict__ w_ih,
    const float* __restrict__ w_hh, const float* __restrict__ v_w,
    const float* __restrict__ dec_w, unsigned short* __restrict__ ws) {
    int i = blockIdx.x * 256 + threadIdx.x;
    if (i >= WS_TOT) return;
    const float* src; int off;
    if (i < WS_WIH)       { src = enc_w; off = WS_ENCW; }
    else if (i < WS_WHH)  { src = w_ih;  off = WS_WIH; }
    else if (i < WS_VW)   { src = w_hh;  off = WS_WHH; }
    else if (i < WS_DECW) { src = v_w;   off = WS_VW; }
    else                  { src = dec_w; off = WS_DECW; }
    ws[i] = f2bf(src[i - off]);
}

// ---------- main fused kernel ----------
// Live subgraph only: enc -> GRU cell -> v -> dec.
// 512 blocks x 4 waves x 32 rows (m=2 tiles of 16): every weight B-fragment
// feeds 2 MFMAs. launch_bounds(256,2) (cap 256 VGPR) so whole load batches
// stay in flight (round-3 collapsed to 64 VGPR -> serialized L2 round-trips).
// Wave-private LDS slice, no __syncthreads.
__global__ __launch_bounds__(256, 2) void attn_critic_kernel(
    const float* __restrict__ obs,    // [SIZE,256] f32
    const float* __restrict__ hid,    // [SIZE,128] f32
    const float* __restrict__ enc_b,  // [128] f32
    const float* __restrict__ b_ih,   // [384] f32
    const float* __restrict__ b_hh,   // [384] f32
    const float* __restrict__ v_b,    // [64] f32
    const float* __restrict__ dec_b,  // [10] f32
    const unsigned short* __restrict__ wsw,  // bf16 weights (ws layout)
    float* __restrict__ out)          // [SIZE*10] ++ [SIZE*128] f32
{
    // cols 0..127: x then h_out; cols 128..191: v. rows 0..15 m=0, 16..31 m=1
    __shared__ __align__(16) unsigned short sB[4][32][192];  // 48 KB

    const unsigned short* encw = wsw + WS_ENCW;
    const unsigned short* wih  = wsw + WS_WIH;
    const unsigned short* whh  = wsw + WS_WHH;
    const unsigned short* vw   = wsw + WS_VW;
    const unsigned short* decw = wsw + WS_DECW;

    const int tid  = threadIdx.x;
    const int wave = tid >> 6;
    const int lane = tid & 63;
    const int l15  = lane & 15;
    const int quad = lane >> 4;
    const int wrow0 = (blockIdx.x * 4 + wave) * 32;
    unsigned short (*S)[192] = sB[wave];

    int rA0 = wrow0 + l15;      rA0 = (rA0 < SIZE) ? rA0 : (SIZE - 1);
    int rA1 = wrow0 + 16 + l15; rA1 = (rA1 < SIZE) ? rA1 : (SIZE - 1);

    // ---- prefetch obs A-fragments for both m-tiles (one latency burst) ----
    bf16x8 aob[2][8];
    {
        const float* o0 = obs + (size_t)rA0 * 256;
        const float* o1 = obs + (size_t)rA1 * 256;
#pragma unroll
        for (int kt = 0; kt < 8; ++kt) {
            aob[0][kt] = cvt8g(o0 + kt * 32 + quad * 8);
            aob[1][kt] = cvt8g(o1 + kt * 32 + quad * 8);
        }
    }

    // ---- Phase 1: X = relu(OBS @ enc_w^T + enc_b) ----
    floatx4 acc1[2][8];
#pragma unroll
    for (int nt = 0; nt < 8; ++nt) {
        acc1[0][nt] = floatx4{0.f, 0.f, 0.f, 0.f};
        acc1[1][nt] = floatx4{0.f, 0.f, 0.f, 0.f};
    }
#pragma unroll 1
    for (int kt = 0; kt < 8; ++kt) {
#pragma unroll
        for (int nt = 0; nt < 8; ++nt) {
            bf16x8 b = ld8(encw + (nt * 16 + l15) * 256 + kt * 32 + quad * 8);
            acc1[0][nt] = __builtin_amdgcn_mfma_f32_16x16x32_bf16(aob[0][kt], b, acc1[0][nt], 0, 0, 0);
            acc1[1][nt] = __builtin_amdgcn_mfma_f32_16x16x32_bf16(aob[1][kt], b, acc1[1][nt], 0, 0, 0);
        }
    }

    // prefetch hid A-fragments (latency hides under phase-1 epilogue)
    bf16x8 hf[2][4];
    {
        const float* h0 = hid + (size_t)rA0 * 128;
        const float* h1 = hid + (size_t)rA1 * 128;
#pragma unroll
        for (int kt = 0; kt < 4; ++kt) {
            hf[0][kt] = cvt8g(h0 + kt * 32 + quad * 8);
            hf[1][kt] = cvt8g(h1 + kt * 32 + quad * 8);
        }
    }

    // phase-1 epilogue -> LDS (bf16 x, A-layout source for phase 2)
#pragma unroll
    for (int nt = 0; nt < 8; ++nt) {
        float bias = enc_b[nt * 16 + l15];
#pragma unroll
        for (int r = 0; r < 4; ++r) {
            S[quad * 4 + r][nt * 16 + l15]      = f2bf(fmaxf(acc1[0][nt][r] + bias, 0.f));
            S[16 + quad * 4 + r][nt * 16 + l15] = f2bf(fmaxf(acc1[1][nt][r] + bias, 0.f));
        }
    }
    bf16x8 xf[2][4];
#pragma unroll
    for (int kt = 0; kt < 4; ++kt) {
        xf[0][kt] = ld8(&S[l15][kt * 32 + quad * 8]);
        xf[1][kt] = ld8(&S[16 + l15][kt * 32 + quad * 8]);
    }

    float* out_h = out + (size_t)SIZE * 10;

    // ---- Phase 2: GRU cell ----
#pragma unroll 1
    for (int nt = 0; nt < 8; ++nt) {
        const int nr = nt * 16 + l15;
        floatx4 gir[2], giz[2], gin[2], ghr[2], ghz[2], ghn[2];
#pragma unroll
        for (int m = 0; m < 2; ++m) {
            gir[m] = floatx4{0.f,0.f,0.f,0.f}; giz[m] = gir[m]; gin[m] = gir[m];
            ghr[m] = gir[m]; ghz[m] = gir[m]; ghn[m] = gir[m];
        }
#pragma unroll
        for (int kt = 0; kt < 4; ++kt) {
            const int ko = kt * 32 + quad * 8;
            bf16x8 bir = ld8(wih + (size_t)(nr)       * 128 + ko);
            bf16x8 biz = ld8(wih + (size_t)(nr + 128) * 128 + ko);
            bf16x8 bin = ld8(wih + (size_t)(nr + 256) * 128 + ko);
            bf16x8 bhr = ld8(whh + (size_t)(nr)       * 128 + ko);
            bf16x8 bhz = ld8(whh + (size_t)(nr + 128) * 128 + ko);
            bf16x8 bhn = ld8(whh + (size_t)(nr + 256) * 128 + ko);
#pragma unroll
            for (int m = 0; m < 2; ++m) {
                gir[m] = __builtin_amdgcn_mfma_f32_16x16x32_bf16(xf[m][kt], bir, gir[m], 0, 0, 0);
                giz[m] = __builtin_amdgcn_mfma_f32_16x16x32_bf16(xf[m][kt], biz, giz[m], 0, 0, 0);
                gin[m] = __builtin_amdgcn_mfma_f32_16x16x32_bf16(xf[m][kt], bin, gin[m], 0, 0, 0);
                ghr[m] = __builtin_amdgcn_mfma_f32_16x16x32_bf16(hf[m][kt], bhr, ghr[m], 0, 0, 0);
                ghz[m] = __builtin_amdgcn_mfma_f32_16x16x32_bf16(hf[m][kt], bhz, ghz[m], 0, 0, 0);
                ghn[m] = __builtin_amdgcn_mfma_f32_16x16x32_bf16(hf[m][kt], bhn, ghn[m], 0, 0, 0);
            }
        }
        const float bir_ = b_ih[nr], biz_ = b_ih[nr + 128], bin_ = b_ih[nr + 256];
        const float bhr_ = b_hh[nr], bhz_ = b_hh[nr + 128], bhn_ = b_hh[nr + 256];
#pragma unroll
        for (int m = 0; m < 2; ++m) {
#pragma unroll
            for (int r = 0; r < 4; ++r) {
                const int grow = wrow0 + m * 16 + quad * 4 + r;
                const int rowc = (grow < SIZE) ? grow : (SIZE - 1);
                float hprev = hid[(size_t)rowc * 128 + nr];
                float rg = sigmf(gir[m][r] + bir_ + ghr[m][r] + bhr_);
                float zg = sigmf(giz[m][r] + biz_ + ghz[m][r] + bhz_);
                float ng = tanhfast(gin[m][r] + bin_ + rg * (ghn[m][r] + bhn_));
                float ho = (1.f - zg) * ng + zg * hprev;
                S[m * 16 + quad * 4 + r][nr] = f2bf(ho);
                if (grow < SIZE) out_h[(size_t)grow * 128 + nr] = ho;
            }
        }
    }

    // ---- Phase 3: V = relu(H_OUT @ v_w^T + v_b) ----
    bf16x8 af[2][4];
#pragma unroll
    for (int kt = 0; kt < 4; ++kt) {
        af[0][kt] = ld8(&S[l15][kt * 32 + quad * 8]);
        af[1][kt] = ld8(&S[16 + l15][kt * 32 + quad * 8]);
    }
#pragma unroll 1
    for (int nt = 0; nt < 4; ++nt) {
        floatx4 a3[2];
        a3[0] = floatx4{0.f, 0.f, 0.f, 0.f}; a3[1] = a3[0];
#pragma unroll
        for (int kt = 0; kt < 4; ++kt) {
            bf16x8 b = ld8(vw + (nt * 16 + l15) * 128 + kt * 32 + quad * 8);
            a3[0] = __builtin_amdgcn_mfma_f32_16x16x32_bf16(af[0][kt], b, a3[0], 0, 0, 0);
            a3[1] = __builtin_amdgcn_mfma_f32_16x16x32_bf16(af[1][kt], b, a3[1], 0, 0, 0);
        }
        float bias = v_b[nt * 16 + l15];
#pragma unroll
        for (int m = 0; m < 2; ++m)
#pragma unroll
            for (int r = 0; r < 4; ++r)
                S[m * 16 + quad * 4 + r][128 + nt * 16 + l15] =
                    f2bf(fmaxf(a3[m][r] + bias, 0.f));
    }

    // ---- Phase 4: OUT = [H_OUT|V] @ dec_w^T + dec_b ----
    {
        floatx4 a4[2];
        a4[0] = floatx4{0.f, 0.f, 0.f, 0.f}; a4[1] = a4[0];
        const int wr = (l15 < 10) ? l15 : 9;
#pragma unroll
        for (int kt = 0; kt < 6; ++kt) {
            bf16x8 b  = ld8(decw + wr * 192 + kt * 32 + quad * 8);
            bf16x8 a0 = ld8(&S[l15][kt * 32 + quad * 8]);
            bf16x8 a1 = ld8(&S[16 + l15][kt * 32 + quad * 8]);
            a4[0] = __builtin_amdgcn_mfma_f32_16x16x32_bf16(a0, b, a4[0], 0, 0, 0);
            a4[1] = __builtin_amdgcn_mfma_f32_16x16x32_bf16(a1, b, a4[1], 0, 0, 0);
        }
        if (l15 < 10) {
            float bias = dec_b[l15];
#pragma unroll
            for (int m = 0; m < 2; ++m)
#pragma unroll
                for (int r = 0; r < 4; ++r) {
                    int grow = wrow0 + m * 16 + quad * 4 + r;
                    if (grow < SIZE) out[(size_t)grow * 10 + l15] = a4[m][r] + bias;
                }
        }
    }
}

extern "C" void kernel_launch(void* const* d_in, const int* in_sizes, int n_in,
                              void* d_out, int out_size, void* d_ws, size_t ws_size,
                              hipStream_t stream) {
    const float* obs   = (const float*)d_in[0];
    const float* hid   = (const float*)d_in[1];
    const float* enc_w = (const float*)d_in[2];
    const float* enc_b = (const float*)d_in[3];
    const float* w_ih  = (const float*)d_in[4];
    const float* w_hh  = (const float*)d_in[5];
    const float* b_ih  = (const float*)d_in[6];
    const float* b_hh  = (const float*)d_in[7];
    // d_in[8..19]: dead code (bi-GRU / hard attention / q,k) — unused.
    const float* v_w   = (const float*)d_in[20];
    const float* v_b   = (const float*)d_in[21];
    const float* dec_w = (const float*)d_in[22];
    const float* dec_b = (const float*)d_in[23];
    unsigned short* wsw = (unsigned short*)d_ws;
    float* out = (float*)d_out;

    hipLaunchKernelGGL(cvt_weights, dim3((WS_TOT + 255) / 256), dim3(256), 0, stream,
                       enc_w, w_ih, w_hh, v_w, dec_w, wsw);
    // 512 blocks x 4 waves x 32 rows = 65536 >= 65535
    hipLaunchKernelGGL(attn_critic_kernel, dim3(512), dim3(256), 0, stream,
                       obs, hid, enc_b, b_ih, b_hh, v_b, dec_b, wsw, out);
}

// Round 5
// 221.226 us; speedup vs baseline: 3.1427x; 1.1573x over previous
//
#include <hip/hip_runtime.h>
#include <stdint.h>

#define SIZE 65535

typedef __bf16 bf16x8 __attribute__((ext_vector_type(8)));
typedef float floatx4 __attribute__((ext_vector_type(4)));

// ws layout (bf16 elements), FRAGMENT-LINEAR: chunk = tile*64 + lane, 8 elems/chunk.
// A B-fragment load is then lanes reading consecutive 16B -> coalesced 1KB/instr.
#define WS_ENCW 0        // [nt8][kt8][lane][8]        -> 32768
#define WS_WIH  32768    // [nt8][g3][kt4][lane][8]    -> 49152
#define WS_WHH  81920    // [nt8][g3][kt4][lane][8]    -> 49152
#define WS_VW   131072   // [nt4][kt4][lane][8]        -> 8192
#define WS_DECW 139264   // [kt6][lane][8] (rows>=10 zero) -> 3072
#define WS_TOTC 17792    // total chunks (x64x8 elems = 142336)

__device__ __forceinline__ unsigned short f2bf(float f) {
    union { float f; unsigned int u; } v; v.f = f;
    unsigned int u = v.u;
    return (unsigned short)((u + 0x7fffu + ((u >> 16) & 1u)) >> 16);
}
__device__ __forceinline__ float bf2f(unsigned short b) {
    union { unsigned int u; float f; } v; v.u = ((unsigned int)b) << 16;
    return v.f;
}
__device__ __forceinline__ float sigmf(float x) {
    x = fminf(fmaxf(x, -30.f), 30.f);
    return 1.f / (1.f + __expf(-x));
}
__device__ __forceinline__ float tanhfast(float x) {
    x = fminf(fmaxf(x, -15.f), 15.f);
    float e = __expf(2.f * x);
    return (e - 1.f) / (e + 1.f);
}

union BF8 { bf16x8 v; unsigned short s[8]; };

__device__ __forceinline__ bf16x8 cvt8g(const float* p) {
    float4 a = *reinterpret_cast<const float4*>(p);
    float4 b = *reinterpret_cast<const float4*>(p + 4);
    BF8 r;
    r.s[0] = f2bf(a.x); r.s[1] = f2bf(a.y); r.s[2] = f2bf(a.z); r.s[3] = f2bf(a.w);
    r.s[4] = f2bf(b.x); r.s[5] = f2bf(b.y); r.s[6] = f2bf(b.z); r.s[7] = f2bf(b.w);
    return r.v;
}
__device__ __forceinline__ bf16x8 ld8(const unsigned short* p) {
    return *reinterpret_cast<const bf16x8*>(p);
}

// ---------- pre-kernel: f32 weights -> bf16 fragment-linear layout ----------
__global__ __launch_bounds__(256) void cvt_weights(
    const float* __restrict__ enc_w, const float* __restrict__ w_ih,
    const float* __restrict__ w_hh, const float* __restrict__ v_w,
    const float* __restrict__ dec_w, unsigned short* __restrict__ ws) {
    int c = blockIdx.x * 256 + threadIdx.x;
    if (c >= WS_TOTC) return;
    const int lane = c & 63;
    const int l = lane & 15;
    const int q = lane >> 4;
    const float* src; int row, col, stride; bool zero = false;
    if (c < 4096) {                      // enc_w [nt8][kt8]
        int lt = c >> 6; int nt = lt >> 3, kt = lt & 7;
        row = nt * 16 + l; col = kt * 32 + q * 8; src = enc_w; stride = 256;
    } else if (c < 10240) {              // w_ih [nt8][g3][kt4]
        int lt = (c - 4096) >> 6; int nt = lt / 12; int r2 = lt % 12;
        int g = r2 >> 2, kt = r2 & 3;
        row = g * 128 + nt * 16 + l; col = kt * 32 + q * 8; src = w_ih; stride = 128;
    } else if (c < 16384) {              // w_hh
        int lt = (c - 10240) >> 6; int nt = lt / 12; int r2 = lt % 12;
        int g = r2 >> 2, kt = r2 & 3;
        row = g * 128 + nt * 16 + l; col = kt * 32 + q * 8; src = w_hh; stride = 128;
    } else if (c < 17408) {              // v_w [nt4][kt4]
        int lt = (c - 16384) >> 6; int nt = lt >> 2, kt = lt & 3;
        row = nt * 16 + l; col = kt * 32 + q * 8; src = v_w; stride = 128;
    } else {                             // dec_w [kt6], zero-pad rows 10..15
        int kt = (c - 17408) >> 6;
        row = l; col = kt * 32 + q * 8; src = dec_w; stride = 192;
        zero = (l >= 10);
    }
    float4 a, b;
    if (zero) { a = make_float4(0.f,0.f,0.f,0.f); b = a; }
    else {
        const float* p = src + (size_t)row * stride + col;
        a = *reinterpret_cast<const float4*>(p);
        b = *reinterpret_cast<const float4*>(p + 4);
    }
    unsigned short* d = ws + (size_t)c * 8;
    d[0]=f2bf(a.x); d[1]=f2bf(a.y); d[2]=f2bf(a.z); d[3]=f2bf(a.w);
    d[4]=f2bf(b.x); d[5]=f2bf(b.y); d[6]=f2bf(b.z); d[7]=f2bf(b.w);
}

// ---------- main fused kernel ----------
// Live subgraph only: enc -> GRU cell -> v -> dec (bi-GRU/gumbel/q,k dead;
// softmax over singleton axis == 1 so x_att == v).
// 512 blocks x 4 waves x 32 rows (m=2). Weight B-frags are coalesced streams
// (fragment-linear ws). LDS strides padded to 272B/144B (2-way only = free).
// All global stores coalesced via LDS staging (no partial-line RMW).
__global__ __launch_bounds__(256, 2) void attn_critic_kernel(
    const float* __restrict__ obs,    // [SIZE,256] f32
    const float* __restrict__ hid,    // [SIZE,128] f32
    const float* __restrict__ enc_b,  // [128] f32
    const float* __restrict__ b_ih,   // [384] f32
    const float* __restrict__ b_hh,   // [384] f32
    const float* __restrict__ v_b,    // [64] f32
    const float* __restrict__ dec_b,  // [10] f32
    const unsigned short* __restrict__ wsw,  // bf16 fragment-linear weights
    float* __restrict__ out)          // [SIZE*10] ++ [SIZE*128] f32
{
    // per-wave slices; strides 136/72 shorts = 272B/144B (16B-aligned, bank+4)
    __shared__ __align__(16) unsigned short sA[4][32][136];  // x then h_out
    __shared__ __align__(16) unsigned short sV[4][32][72];   // v
    __shared__ __align__(16) float sO[4][32][10];            // final logits

    const int tid  = threadIdx.x;
    const int wave = tid >> 6;
    const int lane = tid & 63;
    const int l15  = lane & 15;
    const int quad = lane >> 4;
    const int wrow0 = (blockIdx.x * 4 + wave) * 32;

    int rA0 = wrow0 + l15;      rA0 = (rA0 < SIZE) ? rA0 : (SIZE - 1);
    int rA1 = wrow0 + 16 + l15; rA1 = (rA1 < SIZE) ? rA1 : (SIZE - 1);

    // ---- prefetch obs + hid A-fragments (pinned before phase 1) ----
    bf16x8 aob[2][8], hf[2][4];
    {
        const float* o0 = obs + (size_t)rA0 * 256;
        const float* o1 = obs + (size_t)rA1 * 256;
#pragma unroll
        for (int kt = 0; kt < 8; ++kt) {
            aob[0][kt] = cvt8g(o0 + kt * 32 + quad * 8);
            aob[1][kt] = cvt8g(o1 + kt * 32 + quad * 8);
        }
        const float* h0 = hid + (size_t)rA0 * 128;
        const float* h1 = hid + (size_t)rA1 * 128;
#pragma unroll
        for (int kt = 0; kt < 4; ++kt) {
            hf[0][kt] = cvt8g(h0 + kt * 32 + quad * 8);
            hf[1][kt] = cvt8g(h1 + kt * 32 + quad * 8);
        }
    }
    __builtin_amdgcn_sched_barrier(0);

    // ---- Phase 1: X = relu(OBS @ enc_w^T + enc_b) ----
    {
        const unsigned short* encf = wsw + WS_ENCW + lane * 8;
#pragma unroll 2
        for (int nt = 0; nt < 8; ++nt) {
            floatx4 a0 = floatx4{0.f,0.f,0.f,0.f}, a1 = a0;
#pragma unroll
            for (int kt = 0; kt < 8; ++kt) {
                bf16x8 b = ld8(encf + (size_t)(nt * 8 + kt) * 512);
                a0 = __builtin_amdgcn_mfma_f32_16x16x32_bf16(aob[0][kt], b, a0, 0, 0, 0);
                a1 = __builtin_amdgcn_mfma_f32_16x16x32_bf16(aob[1][kt], b, a1, 0, 0, 0);
            }
            float bias = enc_b[nt * 16 + l15];
#pragma unroll
            for (int r = 0; r < 4; ++r) {
                sA[wave][quad * 4 + r][nt * 16 + l15]      = f2bf(fmaxf(a0[r] + bias, 0.f));
                sA[wave][16 + quad * 4 + r][nt * 16 + l15] = f2bf(fmaxf(a1[r] + bias, 0.f));
            }
        }
    }
    bf16x8 xf[2][4];
#pragma unroll
    for (int kt = 0; kt < 4; ++kt) {
        xf[0][kt] = ld8(&sA[wave][l15][kt * 32 + quad * 8]);
        xf[1][kt] = ld8(&sA[wave][16 + l15][kt * 32 + quad * 8]);
    }

    // ---- Phase 2: GRU cell (h_out bf16 -> sA cols 0..127) ----
    {
        const unsigned short* wihf = wsw + WS_WIH + lane * 8;
        const unsigned short* whhf = wsw + WS_WHH + lane * 8;
#pragma unroll 1
        for (int nt = 0; nt < 8; ++nt) {
            const int nr = nt * 16 + l15;
            floatx4 gi[3][2], gh[3][2];
#pragma unroll
            for (int g = 0; g < 3; ++g) {
                gi[g][0] = floatx4{0.f,0.f,0.f,0.f}; gi[g][1] = gi[g][0];
                gh[g][0] = gi[g][0]; gh[g][1] = gi[g][0];
            }
#pragma unroll
            for (int g = 0; g < 3; ++g)
#pragma unroll
                for (int kt = 0; kt < 4; ++kt) {
                    bf16x8 bi = ld8(wihf + (size_t)((nt * 3 + g) * 4 + kt) * 512);
                    bf16x8 bh = ld8(whhf + (size_t)((nt * 3 + g) * 4 + kt) * 512);
                    gi[g][0] = __builtin_amdgcn_mfma_f32_16x16x32_bf16(xf[0][kt], bi, gi[g][0], 0, 0, 0);
                    gi[g][1] = __builtin_amdgcn_mfma_f32_16x16x32_bf16(xf[1][kt], bi, gi[g][1], 0, 0, 0);
                    gh[g][0] = __builtin_amdgcn_mfma_f32_16x16x32_bf16(hf[0][kt], bh, gh[g][0], 0, 0, 0);
                    gh[g][1] = __builtin_amdgcn_mfma_f32_16x16x32_bf16(hf[1][kt], bh, gh[g][1], 0, 0, 0);
                }
            const float bir_ = b_ih[nr], biz_ = b_ih[nr + 128], bin_ = b_ih[nr + 256];
            const float bhr_ = b_hh[nr], bhz_ = b_hh[nr + 128], bhn_ = b_hh[nr + 256];
#pragma unroll
            for (int m = 0; m < 2; ++m)
#pragma unroll
                for (int r = 0; r < 4; ++r) {
                    const int grow = wrow0 + m * 16 + quad * 4 + r;
                    const int rowc = (grow < SIZE) ? grow : (SIZE - 1);
                    float hprev = hid[(size_t)rowc * 128 + nr];
                    float rg = sigmf(gi[0][m][r] + bir_ + gh[0][m][r] + bhr_);
                    float zg = sigmf(gi[1][m][r] + biz_ + gh[1][m][r] + bhz_);
                    float ng = tanhfast(gi[2][m][r] + bin_ + rg * (gh[2][m][r] + bhn_));
                    float ho = (1.f - zg) * ng + zg * hprev;
                    sA[wave][m * 16 + quad * 4 + r][nr] = f2bf(ho);
                }
        }
    }

    // ---- h_out -> global, coalesced (full lines, float2 8B-aligned) ----
    {
        float* out_h = out + (size_t)SIZE * 10;
#pragma unroll 1
        for (int it = 0; it < 16; ++it) {
            int idx = it * 256 + lane * 4;   // over [32][128]
            int rr = idx >> 7, cc = idx & 127;
            int grow = wrow0 + rr;
            if (grow < SIZE) {
                float2 p0 = make_float2(bf2f(sA[wave][rr][cc]),     bf2f(sA[wave][rr][cc + 1]));
                float2 p1 = make_float2(bf2f(sA[wave][rr][cc + 2]), bf2f(sA[wave][rr][cc + 3]));
                float* dst = out_h + (size_t)grow * 128 + cc;
                *reinterpret_cast<float2*>(dst)     = p0;
                *reinterpret_cast<float2*>(dst + 2) = p1;
            }
        }
    }

    // ---- Phase 3: V = relu(H_OUT @ v_w^T + v_b) -> sV ----
    bf16x8 af[2][4];
#pragma unroll
    for (int kt = 0; kt < 4; ++kt) {
        af[0][kt] = ld8(&sA[wave][l15][kt * 32 + quad * 8]);
        af[1][kt] = ld8(&sA[wave][16 + l15][kt * 32 + quad * 8]);
    }
    {
        const unsigned short* vwf = wsw + WS_VW + lane * 8;
#pragma unroll 1
        for (int nt = 0; nt < 4; ++nt) {
            floatx4 a0 = floatx4{0.f,0.f,0.f,0.f}, a1 = a0;
#pragma unroll
            for (int kt = 0; kt < 4; ++kt) {
                bf16x8 b = ld8(vwf + (size_t)(nt * 4 + kt) * 512);
                a0 = __builtin_amdgcn_mfma_f32_16x16x32_bf16(af[0][kt], b, a0, 0, 0, 0);
                a1 = __builtin_amdgcn_mfma_f32_16x16x32_bf16(af[1][kt], b, a1, 0, 0, 0);
            }
            float bias = v_b[nt * 16 + l15];
#pragma unroll
            for (int r = 0; r < 4; ++r) {
                sV[wave][quad * 4 + r][nt * 16 + l15]      = f2bf(fmaxf(a0[r] + bias, 0.f));
                sV[wave][16 + quad * 4 + r][nt * 16 + l15] = f2bf(fmaxf(a1[r] + bias, 0.f));
            }
        }
    }

    // ---- Phase 4: OUT = [H_OUT|V] @ dec_w^T + dec_b ----
    {
        const unsigned short* decf = wsw + WS_DECW + lane * 8;
        floatx4 d0 = floatx4{0.f,0.f,0.f,0.f}, d1 = d0;
#pragma unroll
        for (int kt = 0; kt < 6; ++kt) {
            bf16x8 b = ld8(decf + (size_t)kt * 512);
            bf16x8 a0 = (kt < 4) ? af[0][kt] : ld8(&sV[wave][l15][(kt - 4) * 32 + quad * 8]);
            bf16x8 a1 = (kt < 4) ? af[1][kt] : ld8(&sV[wave][16 + l15][(kt - 4) * 32 + quad * 8]);
            d0 = __builtin_amdgcn_mfma_f32_16x16x32_bf16(a0, b, d0, 0, 0, 0);
            d1 = __builtin_amdgcn_mfma_f32_16x16x32_bf16(a1, b, d1, 0, 0, 0);
        }
        if (l15 < 10) {
            float bias = dec_b[l15];
#pragma unroll
            for (int r = 0; r < 4; ++r) {
                sO[wave][quad * 4 + r][l15]      = d0[r] + bias;
                sO[wave][16 + quad * 4 + r][l15] = d1[r] + bias;
            }
        }
        // coalesced store: 320 consecutive f32 per wave
#pragma unroll
        for (int j = 0; j < 5; ++j) {
            int idx = j * 64 + lane;          // 0..319
            int row = idx / 10, col = idx % 10;
            int grow = wrow0 + row;
            if (grow < SIZE)
                out[(size_t)grow * 10 + col] = sO[wave][row][col];
        }
    }
}

extern "C" void kernel_launch(void* const* d_in, const int* in_sizes, int n_in,
                              void* d_out, int out_size, void* d_ws, size_t ws_size,
                              hipStream_t stream) {
    const float* obs   = (const float*)d_in[0];
    const float* hid   = (const float*)d_in[1];
    const float* enc_w = (const float*)d_in[2];
    const float* enc_b = (const float*)d_in[3];
    const float* w_ih  = (const float*)d_in[4];
    const float* w_hh  = (const float*)d_in[5];
    const float* b_ih  = (const float*)d_in[6];
    const float* b_hh  = (const float*)d_in[7];
    // d_in[8..19]: dead code (bi-GRU / hard attention / q,k) — unused.
    const float* v_w   = (const float*)d_in[20];
    const float* v_b   = (const float*)d_in[21];
    const float* dec_w = (const float*)d_in[22];
    const float* dec_b = (const float*)d_in[23];
    unsigned short* wsw = (unsigned short*)d_ws;
    float* out = (float*)d_out;

    hipLaunchKernelGGL(cvt_weights, dim3((WS_TOTC + 255) / 256), dim3(256), 0, stream,
                       enc_w, w_ih, w_hh, v_w, dec_w, wsw);
    // 512 blocks x 4 waves x 32 rows = 65536 >= 65535
    hipLaunchKernelGGL(attn_critic_kernel, dim3(512), dim3(256), 0, stream,
                       obs, hid, enc_b, b_ih, b_hh, v_b, dec_b, wsw, out);
}